// Round 1
// baseline (437.099 us; speedup 1.0000x reference)
//
#include <hip/hip_runtime.h>

typedef __bf16 bf16x8 __attribute__((ext_vector_type(8)));
typedef float f32x4 __attribute__((ext_vector_type(4)));
typedef unsigned short u16;
typedef unsigned int u32;

constexpr int Bc = 4, Sc = 2048, Dc = 1024, Hc = 16, DHc = 64;
constexpr int Mrows = Bc * Sc;  // 8192

__device__ __forceinline__ u16 f2bf(float f) {
  u32 u = __float_as_uint(f);
  u = (u + 0x7fffu + ((u >> 16) & 1u)) >> 16;  // RTNE
  return (u16)u;
}

#define LDSP(p) ((__attribute__((address_space(3))) void*)(p))
#define GLBP(p) ((const __attribute__((address_space(1))) void*)(p))

// ---------------- fp32 -> bf16 conversion ----------------
__global__ __launch_bounds__(256) void cvt_kernel(const float* __restrict__ in,
                                                  u16* __restrict__ out, int n4) {
  int stride = gridDim.x * blockDim.x;
  for (int i = blockIdx.x * blockDim.x + threadIdx.x; i < n4; i += stride) {
    float4 v = reinterpret_cast<const float4*>(in)[i];
    ushort4 o;
    o.x = f2bf(v.x); o.y = f2bf(v.y); o.z = f2bf(v.z); o.w = f2bf(v.w);
    reinterpret_cast<ushort4*>(out)[i] = o;
  }
}

// ---------------- GEMM: C[m,n] = sum_k A[m,k]*Bt[n,k] + bias[n] ----------------
// m97 structure: 128x128 tile, BK=32, 4 waves (2x2 of 64x64), global_load_lds w16.
enum GemmMode { MODE_Q = 0, MODE_K = 1, MODE_V = 2, MODE_OUT = 3 };

template <int MODE>
__global__ __launch_bounds__(256) void gemm_bt(const u16* __restrict__ A, const u16* __restrict__ Bt,
                                               const float* __restrict__ bias, void* __restrict__ Cout,
                                               int M, int N, int K) {
  __shared__ u16 As[128 * 32];
  __shared__ u16 Bs[128 * 32];
  const int tiles_n = N >> 7;
  const int tm = blockIdx.x / tiles_n, tn = blockIdx.x % tiles_n;
  const int t = threadIdx.x, w = t >> 6, l = t & 63;
  const int row0 = tm << 7, col0 = tn << 7;
  const int slr = l >> 2, slc = (l & 3) << 3;       // staging: 4 lanes/row of 64B
  const int wr = (w >> 1) << 6, wc = (w & 1) << 6;  // wave 64x64 subtile
  const int fr = l & 15, fo = (l >> 4) << 3;        // fragment row / k-offset

  f32x4 acc[4][4] = {};

  for (int kt = 0; kt < K; kt += 32) {
    __syncthreads();
#pragma unroll
    for (int i = 0; i < 2; ++i) {
      const int rb = (i << 6) + (w << 4);  // wave-uniform 16-row chunk
      __builtin_amdgcn_global_load_lds(GLBP(A + (size_t)(row0 + rb + slr) * K + kt + slc),
                                       LDSP(&As[rb * 32]), 16, 0, 0);
      __builtin_amdgcn_global_load_lds(GLBP(Bt + (size_t)(col0 + rb + slr) * K + kt + slc),
                                       LDSP(&Bs[rb * 32]), 16, 0, 0);
    }
    __syncthreads();
    bf16x8 af[4], bfr[4];
#pragma unroll
    for (int mi = 0; mi < 4; ++mi) af[mi] = *(const bf16x8*)&As[(wr + mi * 16 + fr) * 32 + fo];
#pragma unroll
    for (int ni = 0; ni < 4; ++ni) bfr[ni] = *(const bf16x8*)&Bs[(wc + ni * 16 + fr) * 32 + fo];
#pragma unroll
    for (int mi = 0; mi < 4; ++mi)
#pragma unroll
      for (int ni = 0; ni < 4; ++ni)
        acc[mi][ni] = __builtin_amdgcn_mfma_f32_16x16x32_bf16(af[mi], bfr[ni], acc[mi][ni], 0, 0, 0);
  }

  // epilogue: C/D layout col = lane&15, row = (lane>>4)*4 + i  [m89/m91 verified]
  const int rgrp = (l >> 4) << 2;
#pragma unroll
  for (int ni = 0; ni < 4; ++ni) {
    const int n = col0 + wc + ni * 16 + fr;
    const float bv = bias[n];
#pragma unroll
    for (int mi = 0; mi < 4; ++mi) {
      const int mbase = row0 + wr + mi * 16 + rgrp;
      if (MODE == MODE_OUT) {
        float* O = (float*)Cout;
#pragma unroll
        for (int i = 0; i < 4; ++i) O[(size_t)(mbase + i) * N + n] = acc[mi][ni][i] + bv;
      } else if (MODE == MODE_V) {
        // V transposed: Vt[((b*H+h)*DH + dh)*S + s]; 4 consecutive s -> packed 8B store
        const int b = mbase >> 11, s = mbase & (Sc - 1);
        const int h = n >> 6, dh = n & 63;
        u16* Vt = (u16*)Cout;
        ushort4 pk;
        pk.x = f2bf(acc[mi][ni][0] + bv);
        pk.y = f2bf(acc[mi][ni][1] + bv);
        pk.z = f2bf(acc[mi][ni][2] + bv);
        pk.w = f2bf(acc[mi][ni][3] + bv);
        *(ushort4*)&Vt[((size_t)((b * Hc + h) * DHc + dh)) * Sc + s] = pk;
      } else {
        u16* Oh = (u16*)Cout;  // Qh/Kh: [((b*H+h)*S + s)*DH + dh]
#pragma unroll
        for (int i = 0; i < 4; ++i) {
          const int m = mbase + i;
          const int b = m >> 11, s = m & (Sc - 1);
          const int h = n >> 6, dh = n & 63;
          float vv = acc[mi][ni][i] + bv;
          if (MODE == MODE_Q) vv *= 0.125f;  // fold 1/sqrt(DH)
          Oh[((size_t)((b * Hc + h) * Sc + s)) * DHc + dh] = f2bf(vv);
        }
      }
    }
  }
}

// ---------------- Flash attention ----------------
// block: 256 thr (4 waves), 128 Q rows per block (32/wave), KV tiles of 64.
// Padded LDS (LD=72 elems = 144B rows) -> balanced banks for b128 reads/writes.
constexpr int LDK = 72;

__global__ __launch_bounds__(256) void attn_kernel(const u16* __restrict__ Qh, const u16* __restrict__ Kh,
                                                   const u16* __restrict__ Vt, u16* __restrict__ ctx) {
  __shared__ u16 Ks[64 * LDK];
  __shared__ u16 Vs[64 * LDK];
  __shared__ u16 Ps[128 * LDK];

  const int bid = blockIdx.x;
  const int qt = bid & 15, bh = bid >> 4;  // 16 q-tiles, 64 (b,h)
  const int t = threadIdx.x, w = t >> 6, l = t & 63;
  const int fr = l & 15, fo = (l >> 4) << 3;

  // Q fragments straight from global (Q read once; scale already folded in)
  bf16x8 qf[2][2];
#pragma unroll
  for (int mi = 0; mi < 2; ++mi)
#pragma unroll
    for (int kk = 0; kk < 2; ++kk)
      qf[mi][kk] = *(const bf16x8*)(Qh + ((size_t)bh * Sc + qt * 128 + w * 32 + mi * 16 + fr) * DHc +
                                    kk * 32 + fo);

  f32x4 o_acc[2][4] = {};
  float m_run[2][4], l_run[2][4];
#pragma unroll
  for (int mi = 0; mi < 2; ++mi)
#pragma unroll
    for (int i = 0; i < 4; ++i) { m_run[mi][i] = -3.0e38f; l_run[mi][i] = 0.f; }

  const int srow = t >> 3, scol = (t & 7) << 3;  // staging: 8 lanes/row of 128B

  for (int kt = 0; kt < Sc; kt += 64) {
    __syncthreads();
#pragma unroll
    for (int p = 0; p < 2; ++p) {  // reg-stage K and V^T tiles (coalesced 16B loads)
      const int r = p * 32 + srow;
      uint4 kv = *(const uint4*)(Kh + ((size_t)bh * Sc + kt + r) * DHc + scol);
      uint4 vv = *(const uint4*)(Vt + ((size_t)bh * DHc + r) * Sc + kt + scol);
      *(uint4*)&Ks[r * LDK + scol] = kv;
      *(uint4*)&Vs[r * LDK + scol] = vv;
    }
    __syncthreads();

    // S = Q K^T  (scaled Q)
    f32x4 sacc[2][4] = {};
#pragma unroll
    for (int ni = 0; ni < 4; ++ni)
#pragma unroll
      for (int kk = 0; kk < 2; ++kk) {
        bf16x8 kf = *(const bf16x8*)&Ks[(ni * 16 + fr) * LDK + kk * 32 + fo];
#pragma unroll
        for (int mi = 0; mi < 2; ++mi)
          sacc[mi][ni] = __builtin_amdgcn_mfma_f32_16x16x32_bf16(qf[mi][kk], kf, sacc[mi][ni], 0, 0, 0);
      }

    // online softmax (rows live on lanes sharing l>>4; reduce across l&15)
#pragma unroll
    for (int mi = 0; mi < 2; ++mi) {
#pragma unroll
      for (int i = 0; i < 4; ++i) {
        float mx = fmaxf(fmaxf(sacc[mi][0][i], sacc[mi][1][i]), fmaxf(sacc[mi][2][i], sacc[mi][3][i]));
#pragma unroll
        for (int d = 1; d < 16; d <<= 1) mx = fmaxf(mx, __shfl_xor(mx, d));
        const float mnew = fmaxf(m_run[mi][i], mx);
        const float corr = __expf(m_run[mi][i] - mnew);
        m_run[mi][i] = mnew;
        float sum = 0.f;
#pragma unroll
        for (int ni = 0; ni < 4; ++ni) {
          float pv = __expf(sacc[mi][ni][i] - mnew);
          sacc[mi][ni][i] = pv;
          sum += pv;
        }
#pragma unroll
        for (int d = 1; d < 16; d <<= 1) sum += __shfl_xor(sum, d);
        l_run[mi][i] = l_run[mi][i] * corr + sum;
#pragma unroll
        for (int df = 0; df < 4; ++df) o_acc[mi][df][i] *= corr;
      }
      // P -> LDS (re-layout for PV A-operand)
      const int prow = w * 32 + mi * 16 + ((l >> 4) << 2);
#pragma unroll
      for (int ni = 0; ni < 4; ++ni)
#pragma unroll
        for (int i = 0; i < 4; ++i)
          Ps[(prow + i) * LDK + ni * 16 + fr] = f2bf(sacc[mi][ni][i]);
    }
    __syncthreads();

    // O += P V
#pragma unroll
    for (int kk = 0; kk < 2; ++kk) {
      bf16x8 pf[2], vf[4];
#pragma unroll
      for (int mi = 0; mi < 2; ++mi)
        pf[mi] = *(const bf16x8*)&Ps[(w * 32 + mi * 16 + fr) * LDK + kk * 32 + fo];
#pragma unroll
      for (int df = 0; df < 4; ++df)
        vf[df] = *(const bf16x8*)&Vs[(df * 16 + fr) * LDK + kk * 32 + fo];
#pragma unroll
      for (int mi = 0; mi < 2; ++mi)
#pragma unroll
        for (int df = 0; df < 4; ++df)
          o_acc[mi][df] = __builtin_amdgcn_mfma_f32_16x16x32_bf16(pf[mi], vf[df], o_acc[mi][df], 0, 0, 0);
    }
  }

  // write ctx in (B,S,D) bf16 layout (feeds out-proj GEMM directly)
  const int b = bh >> 4, h = bh & 15;
#pragma unroll
  for (int mi = 0; mi < 2; ++mi)
#pragma unroll
    for (int df = 0; df < 4; ++df)
#pragma unroll
      for (int i = 0; i < 4; ++i) {
        const int qrow = qt * 128 + w * 32 + mi * 16 + ((l >> 4) << 2) + i;
        const int dh = df * 16 + fr;
        ctx[((size_t)(b * Sc + qrow)) * Dc + h * DHc + dh] = f2bf(o_acc[mi][df][i] / l_run[mi][i]);
      }
}

// ---------------- launcher ----------------
extern "C" void kernel_launch(void* const* d_in, const int* in_sizes, int n_in,
                              void* d_out, int out_size, void* d_ws, size_t ws_size,
                              hipStream_t stream) {
  const float* q  = (const float*)d_in[0];
  const float* k  = (const float*)d_in[1];
  const float* v  = (const float*)d_in[2];
  const float* Wq = (const float*)d_in[3];
  const float* bq = (const float*)d_in[4];
  const float* Wk = (const float*)d_in[5];
  const float* bk = (const float*)d_in[6];
  const float* Wv = (const float*)d_in[7];
  const float* bv = (const float*)d_in[8];
  const float* Wo = (const float*)d_in[9];
  const float* bo = (const float*)d_in[10];
  float* out = (float*)d_out;

  const size_t MK = (size_t)Mrows * Dc;  // 8,388,608 elems
  const size_t WK = (size_t)Dc * Dc;     // 1,048,576 elems
  u16* qb  = (u16*)d_ws;
  u16* kb  = qb + MK;
  u16* vb  = kb + MK;
  u16* Wqb = vb + MK;
  u16* Wkb = Wqb + WK;
  u16* Wvb = Wkb + WK;
  u16* Wob = Wvb + WK;
  u16* Qh  = Wob + WK;
  u16* Kh  = Qh + MK;
  u16* VtB = Kh + MK;
  u16* ctx = VtB + MK;
  // total ws use: 7*16MB + 4*2MB = ~126 MB

  cvt_kernel<<<2048, 256, 0, stream>>>(q, qb, (int)(MK / 4));
  cvt_kernel<<<2048, 256, 0, stream>>>(k, kb, (int)(MK / 4));
  cvt_kernel<<<2048, 256, 0, stream>>>(v, vb, (int)(MK / 4));
  cvt_kernel<<<512, 256, 0, stream>>>(Wq, Wqb, (int)(WK / 4));
  cvt_kernel<<<512, 256, 0, stream>>>(Wk, Wkb, (int)(WK / 4));
  cvt_kernel<<<512, 256, 0, stream>>>(Wv, Wvb, (int)(WK / 4));
  cvt_kernel<<<512, 256, 0, stream>>>(Wo, Wob, (int)(WK / 4));

  gemm_bt<MODE_Q><<<512, 256, 0, stream>>>(qb, Wqb, bq, (void*)Qh, Mrows, Dc, Dc);
  gemm_bt<MODE_K><<<512, 256, 0, stream>>>(kb, Wkb, bk, (void*)Kh, Mrows, Dc, Dc);
  gemm_bt<MODE_V><<<512, 256, 0, stream>>>(vb, Wvb, bv, (void*)VtB, Mrows, Dc, Dc);

  attn_kernel<<<1024, 256, 0, stream>>>(Qh, Kh, VtB, ctx);

  gemm_bt<MODE_OUT><<<512, 256, 0, stream>>>(ctx, Wob, bo, (void*)out, Mrows, Dc, Dc);
}

// Round 2
// 275.633 us; speedup vs baseline: 1.5858x; 1.5858x over previous
//
#include <hip/hip_runtime.h>

typedef __bf16 bf16x8 __attribute__((ext_vector_type(8)));
typedef __bf16 bf16x4 __attribute__((ext_vector_type(4)));
typedef _Float16 f16x4v __attribute__((ext_vector_type(4)));
typedef float f32x4 __attribute__((ext_vector_type(4)));
typedef float f32x16 __attribute__((ext_vector_type(16)));
typedef unsigned short u16;
typedef unsigned int u32;

constexpr int Bc = 4, Sc = 2048, Dc = 1024, Hc = 16, DHc = 64;
constexpr int Mrows = Bc * Sc;  // 8192

__device__ __forceinline__ u16 f2bf(float f) {
  u32 u = __float_as_uint(f);
  u = (u + 0x7fffu + ((u >> 16) & 1u)) >> 16;  // RTNE
  return (u16)u;
}

#define LDSP(p) ((__attribute__((address_space(3))) void*)(p))
#define GLBP(p) ((const __attribute__((address_space(1))) void*)(p))

// ---------------- fp32 -> bf16 conversion ----------------
__global__ __launch_bounds__(256) void cvt_kernel(const float* __restrict__ in,
                                                  u16* __restrict__ out, int n4) {
  int stride = gridDim.x * blockDim.x;
  for (int i = blockIdx.x * blockDim.x + threadIdx.x; i < n4; i += stride) {
    float4 v = reinterpret_cast<const float4*>(in)[i];
    ushort4 o;
    o.x = f2bf(v.x); o.y = f2bf(v.y); o.z = f2bf(v.z); o.w = f2bf(v.w);
    reinterpret_cast<ushort4*>(out)[i] = o;
  }
}

// ---------------- GEMM: C[m,n] = sum_k A[m,k]*Bt[n,k] + bias[n] ----------------
enum GemmMode { MODE_Q = 0, MODE_K = 1, MODE_V = 2, MODE_OUT = 3 };

template <int MODE>
__global__ __launch_bounds__(256) void gemm_bt(const u16* __restrict__ A, const u16* __restrict__ Bt,
                                               const float* __restrict__ bias, void* __restrict__ Cout,
                                               int M, int N, int K) {
  __shared__ u16 As[128 * 32];
  __shared__ u16 Bs[128 * 32];
  const int tiles_n = N >> 7;
  const int tm = blockIdx.x / tiles_n, tn = blockIdx.x % tiles_n;
  const int t = threadIdx.x, w = t >> 6, l = t & 63;
  const int row0 = tm << 7, col0 = tn << 7;
  const int slr = l >> 2, slc = (l & 3) << 3;
  const int wr = (w >> 1) << 6, wc = (w & 1) << 6;
  const int fr = l & 15, fo = (l >> 4) << 3;

  f32x4 acc[4][4] = {};

  for (int kt = 0; kt < K; kt += 32) {
    __syncthreads();
#pragma unroll
    for (int i = 0; i < 2; ++i) {
      const int rb = (i << 6) + (w << 4);
      __builtin_amdgcn_global_load_lds(GLBP(A + (size_t)(row0 + rb + slr) * K + kt + slc),
                                       LDSP(&As[rb * 32]), 16, 0, 0);
      __builtin_amdgcn_global_load_lds(GLBP(Bt + (size_t)(col0 + rb + slr) * K + kt + slc),
                                       LDSP(&Bs[rb * 32]), 16, 0, 0);
    }
    __syncthreads();
    bf16x8 af[4], bfr[4];
#pragma unroll
    for (int mi = 0; mi < 4; ++mi) af[mi] = *(const bf16x8*)&As[(wr + mi * 16 + fr) * 32 + fo];
#pragma unroll
    for (int ni = 0; ni < 4; ++ni) bfr[ni] = *(const bf16x8*)&Bs[(wc + ni * 16 + fr) * 32 + fo];
#pragma unroll
    for (int mi = 0; mi < 4; ++mi)
#pragma unroll
      for (int ni = 0; ni < 4; ++ni)
        acc[mi][ni] = __builtin_amdgcn_mfma_f32_16x16x32_bf16(af[mi], bfr[ni], acc[mi][ni], 0, 0, 0);
  }

  const int rgrp = (l >> 4) << 2;
#pragma unroll
  for (int ni = 0; ni < 4; ++ni) {
    const int n = col0 + wc + ni * 16 + fr;
    const float bv = bias[n];
#pragma unroll
    for (int mi = 0; mi < 4; ++mi) {
      const int mbase = row0 + wr + mi * 16 + rgrp;
      if (MODE == MODE_OUT) {
        float* O = (float*)Cout;
#pragma unroll
        for (int i = 0; i < 4; ++i) O[(size_t)(mbase + i) * N + n] = acc[mi][ni][i] + bv;
      } else if (MODE == MODE_V) {
        // V transposed + f16: Vt[((b*H+h)*DH + dh)*S + s]
        const int b = mbase >> 11, s = mbase & (Sc - 1);
        const int h = n >> 6, dh = n & 63;
        u16* Vt = (u16*)Cout;
        f16x4v pk;
#pragma unroll
        for (int i = 0; i < 4; ++i) pk[i] = (_Float16)(acc[mi][ni][i] + bv);
        *(f16x4v*)&Vt[((size_t)((b * Hc + h) * DHc + dh)) * Sc + s] = pk;
      } else {
        u16* Oh = (u16*)Cout;  // Qh/Kh: [((b*H+h)*S + s)*DH + dh]
#pragma unroll
        for (int i = 0; i < 4; ++i) {
          const int m = mbase + i;
          const int b = m >> 11, s = m & (Sc - 1);
          const int h = n >> 6, dh = n & 63;
          float vv = acc[mi][ni][i] + bv;
          if (MODE == MODE_Q) vv *= 0.125f * 1.44269504089f;  // fold 1/sqrt(DH) * log2(e)
          Oh[((size_t)((b * Hc + h) * Sc + s)) * DHc + dh] = f2bf(vv);
        }
      }
    }
  }
}

// ---------------- Flash attention v2: swapped-operand, in-register softmax ----------------
// 4 waves/block, 32 q-rows/wave (128/block). KV tiles of 64. QK: mfma_32x32x16_bf16 (S^T),
// PV: mfma_32x32x8f16 (O^T) with P staying in registers. K/V LDS tiles swizzled at 16B
// granules (g ^= row&7) via source-pre-swizzled global_load_lds.
__global__ __launch_bounds__(256, 2) void attn2_kernel(const u16* __restrict__ Qh,
                                                       const u16* __restrict__ Kh,
                                                       const u16* __restrict__ Vt,
                                                       u16* __restrict__ ctx) {
  __shared__ u16 smem[8192];       // 16 KB: K[64][64] bf16 | V^T[64][64] f16 (reused by epilogue)
  u16* K_lds = smem;
  u16* V_lds = smem + 4096;

  const int wid = (blockIdx.x & 7) * 128 + (blockIdx.x >> 3);  // XCD-chunked swizzle (1024%8==0)
  const int qt = wid & 15, bh = wid >> 4;
  const int t = threadIdx.x, w = t >> 6, l = t & 63;
  const int q = l & 31, h = l >> 5;
  const int q0 = qt * 128 + w * 32;

  // Q B-fragments (scale & log2e folded at projection): Q[q0+q][kk*16 + h*8 + j]
  bf16x8 qf[4];
  {
    const u16* qp = Qh + ((size_t)bh * Sc + q0 + q) * DHc + h * 8;
#pragma unroll
    for (int kk = 0; kk < 4; ++kk) qf[kk] = *(const bf16x8*)(qp + kk * 16);
  }

  f32x16 oacc[2] = {};             // O^T[dh_local][q] per dt half
  float m_run = -3.0e38f, l_run = 0.f;

  const int lrow = l >> 3, lg = l & 7;

  for (int kt = 0; kt < Sc; kt += 64) {
    __syncthreads();
#pragma unroll
    for (int c = 0; c < 2; ++c) {
      const int rb = w * 16 + c * 8;
      const int row = rb + lrow;
      const int sg = lg ^ (row & 7);  // pre-swizzle source so linear LDS write = swizzled layout
      __builtin_amdgcn_global_load_lds(GLBP(Kh + ((size_t)bh * Sc + kt + row) * DHc + sg * 8),
                                       LDSP(&K_lds[rb * 64]), 16, 0, 0);
      __builtin_amdgcn_global_load_lds(GLBP(Vt + ((size_t)bh * DHc + row) * Sc + kt + sg * 8),
                                       LDSP(&V_lds[rb * 64]), 16, 0, 0);
    }
    __syncthreads();

    // S^T[k][q] = K · Q^T  (rows = k, cols = q = lane&31)
    f32x16 sacc[2];
#pragma unroll
    for (int kt32 = 0; kt32 < 2; ++kt32) {
      f32x16 s_ = {};
      const int krow = kt32 * 32 + q;
#pragma unroll
      for (int kk = 0; kk < 4; ++kk) {
        bf16x8 kf = *(const bf16x8*)&K_lds[krow * 64 + ((2 * kk + h) ^ (krow & 7)) * 8];
        s_ = __builtin_amdgcn_mfma_f32_32x32x16_bf16(kf, qf[kk], s_, 0, 0, 0);
      }
      sacc[kt32] = s_;
    }

    // online softmax in log2 domain; q-row is lane-local
    float mx = sacc[0][0];
#pragma unroll
    for (int r = 1; r < 16; ++r) mx = fmaxf(mx, sacc[0][r]);
#pragma unroll
    for (int r = 0; r < 16; ++r) mx = fmaxf(mx, sacc[1][r]);
    mx = fmaxf(mx, __shfl_xor(mx, 32));
    const float mnew = fmaxf(m_run, mx);
    const float corr = __builtin_amdgcn_exp2f(m_run - mnew);
    m_run = mnew;
    float sum = 0.f;
    f16x4v pa[2][4];  // P fragments for PV, k = kt32*32 + kc*8 + 4h + j
#pragma unroll
    for (int kt32 = 0; kt32 < 2; ++kt32)
#pragma unroll
      for (int kc = 0; kc < 4; ++kc)
#pragma unroll
        for (int j = 0; j < 4; ++j) {
          float pv = __builtin_amdgcn_exp2f(sacc[kt32][kc * 4 + j] - mnew);
          sum += pv;
          pa[kt32][kc][j] = (_Float16)pv;
        }
    sum += __shfl_xor(sum, 32);
    l_run = l_run * corr + sum;
#pragma unroll
    for (int dt = 0; dt < 2; ++dt)
#pragma unroll
      for (int r = 0; r < 16; ++r) oacc[dt][r] *= corr;

    // O^T += V^T · P : A = V^T rows (dh), B = P cols (q); corr stays lane-local
#pragma unroll
    for (int kt32 = 0; kt32 < 2; ++kt32)
#pragma unroll
      for (int kc = 0; kc < 4; ++kc)
#pragma unroll
        for (int dt = 0; dt < 2; ++dt) {
          const int vrow = dt * 32 + q;
          f16x4v vf = *(const f16x4v*)&V_lds[vrow * 64 + ((kt32 * 4 + kc) ^ (vrow & 7)) * 8 + 4 * h];
          oacc[dt] = __builtin_amdgcn_mfma_f32_32x32x8f16(vf, pa[kt32][kc], oacc[dt], 0, 0, 0);
        }
  }

  // epilogue: normalize, transpose O^T -> O through LDS, coalesced ctx write
  __syncthreads();
  const float inv = 1.f / l_run;
  u16* E = smem + w * 2048;  // per-wave 4 KB: [32 q][64 dh] bf16, 16B-granule swizzled by q
#pragma unroll
  for (int dt = 0; dt < 2; ++dt)
#pragma unroll
    for (int rg = 0; rg < 4; ++rg) {
      bf16x4 pk;
#pragma unroll
      for (int j = 0; j < 4; ++j) pk[j] = (__bf16)(oacc[dt][rg * 4 + j] * inv);
      const int dh0 = dt * 32 + rg * 8 + 4 * h;
      int byte = q * 128 + dh0 * 2;
      byte ^= (q & 7) << 4;
      *(bf16x4*)((char*)E + byte) = pk;
    }
  __syncthreads();
  const int b = bh >> 4, head = bh & 15;
  const size_t crow = ((size_t)(b * Sc + q0 + q)) * Dc + head * 64 + h * 32;
#pragma unroll
  for (int i = 0; i < 4; ++i) {
    const int g = (4 * h + i) ^ (q & 7);
    uint4 tv = *(const uint4*)((char*)E + q * 128 + g * 16);
    *(uint4*)((u16*)ctx + crow + i * 8) = tv;
  }
}

// ---------------- launcher ----------------
extern "C" void kernel_launch(void* const* d_in, const int* in_sizes, int n_in,
                              void* d_out, int out_size, void* d_ws, size_t ws_size,
                              hipStream_t stream) {
  const float* q  = (const float*)d_in[0];
  const float* k  = (const float*)d_in[1];
  const float* v  = (const float*)d_in[2];
  const float* Wq = (const float*)d_in[3];
  const float* bq = (const float*)d_in[4];
  const float* Wk = (const float*)d_in[5];
  const float* bk = (const float*)d_in[6];
  const float* Wv = (const float*)d_in[7];
  const float* bv = (const float*)d_in[8];
  const float* Wo = (const float*)d_in[9];
  const float* bo = (const float*)d_in[10];
  float* out = (float*)d_out;

  const size_t MK = (size_t)Mrows * Dc;
  const size_t WK = (size_t)Dc * Dc;
  u16* qb  = (u16*)d_ws;
  u16* kb  = qb + MK;
  u16* vb  = kb + MK;
  u16* Wqb = vb + MK;
  u16* Wkb = Wqb + WK;
  u16* Wvb = Wkb + WK;
  u16* Wob = Wvb + WK;
  u16* Qh  = Wob + WK;
  u16* Kh  = Qh + MK;
  u16* VtB = Kh + MK;
  u16* ctx = VtB + MK;

  cvt_kernel<<<2048, 256, 0, stream>>>(q, qb, (int)(MK / 4));
  cvt_kernel<<<2048, 256, 0, stream>>>(k, kb, (int)(MK / 4));
  cvt_kernel<<<2048, 256, 0, stream>>>(v, vb, (int)(MK / 4));
  cvt_kernel<<<512, 256, 0, stream>>>(Wq, Wqb, (int)(WK / 4));
  cvt_kernel<<<512, 256, 0, stream>>>(Wk, Wkb, (int)(WK / 4));
  cvt_kernel<<<512, 256, 0, stream>>>(Wv, Wvb, (int)(WK / 4));
  cvt_kernel<<<512, 256, 0, stream>>>(Wo, Wob, (int)(WK / 4));

  gemm_bt<MODE_Q><<<512, 256, 0, stream>>>(qb, Wqb, bq, (void*)Qh, Mrows, Dc, Dc);
  gemm_bt<MODE_K><<<512, 256, 0, stream>>>(kb, Wkb, bk, (void*)Kh, Mrows, Dc, Dc);
  gemm_bt<MODE_V><<<512, 256, 0, stream>>>(vb, Wvb, bv, (void*)VtB, Mrows, Dc, Dc);

  attn2_kernel<<<1024, 256, 0, stream>>>(Qh, Kh, VtB, ctx);

  gemm_bt<MODE_OUT><<<512, 256, 0, stream>>>(ctx, Wob, bo, (void*)out, Mrows, Dc, Dc);
}

// Round 3
// 233.174 us; speedup vs baseline: 1.8746x; 1.1821x over previous
//
#include <hip/hip_runtime.h>

typedef __bf16 bf16x8 __attribute__((ext_vector_type(8)));
typedef __bf16 bf16x4 __attribute__((ext_vector_type(4)));
typedef _Float16 f16x4v __attribute__((ext_vector_type(4)));
typedef float f32x4 __attribute__((ext_vector_type(4)));
typedef float f32x16 __attribute__((ext_vector_type(16)));
typedef unsigned short u16;
typedef unsigned int u32;

constexpr int Bc = 4, Sc = 2048, Dc = 1024, Hc = 16, DHc = 64;
constexpr int Mrows = Bc * Sc;  // 8192

__device__ __forceinline__ u16 f2bf(float f) {
  u32 u = __float_as_uint(f);
  u = (u + 0x7fffu + ((u >> 16) & 1u)) >> 16;  // RTNE
  return (u16)u;
}

#define LDSP(p) ((__attribute__((address_space(3))) void*)(p))
#define GLBP(p) ((const __attribute__((address_space(1))) void*)(p))

// ---------------- fp32 -> bf16 conversion (fused: 3-way / 4-way via blockIdx.y) ------
__global__ __launch_bounds__(256) void cvt3_kernel(const float* __restrict__ a,
                                                   const float* __restrict__ b,
                                                   const float* __restrict__ c,
                                                   ushort4* __restrict__ out, int n4) {
  const float4* in = (const float4*)(blockIdx.y == 0 ? a : blockIdx.y == 1 ? b : c);
  ushort4* o = out + (size_t)blockIdx.y * n4;
  int stride = gridDim.x * blockDim.x;
  for (int i = blockIdx.x * blockDim.x + threadIdx.x; i < n4; i += stride) {
    float4 v = in[i];
    ushort4 r;
    r.x = f2bf(v.x); r.y = f2bf(v.y); r.z = f2bf(v.z); r.w = f2bf(v.w);
    o[i] = r;
  }
}

__global__ __launch_bounds__(256) void cvt4_kernel(const float* __restrict__ a,
                                                   const float* __restrict__ b,
                                                   const float* __restrict__ c,
                                                   const float* __restrict__ d,
                                                   ushort4* __restrict__ out, int n4) {
  const float4* in = (const float4*)(blockIdx.y == 0 ? a : blockIdx.y == 1 ? b
                                     : blockIdx.y == 2 ? c : d);
  ushort4* o = out + (size_t)blockIdx.y * n4;
  int stride = gridDim.x * blockDim.x;
  for (int i = blockIdx.x * blockDim.x + threadIdx.x; i < n4; i += stride) {
    float4 v = in[i];
    ushort4 r;
    r.x = f2bf(v.x); r.y = f2bf(v.y); r.z = f2bf(v.z); r.w = f2bf(v.w);
    o[i] = r;
  }
}

// ---------------- GEMM v2: C[m,n] = sum_k A[m,k]*Bt[n,k] + bias[n] ----------------
// 256x128 tile, BK=32, 512 thr (8 waves = 4M x 2N, wave out 64x64).
// Ring-5 LDS (120KB), stage-ahead-4 via global_load_lds, counted vmcnt(12),
// raw s_barrier (no compiler vmcnt(0) drain), swizzled LDS (64B rows):
//   lds_byte(r,c) = r*64 + (c ^ (((r>>1)&3)<<4))   -> conflict-free b128 frag reads.
enum GemmMode { MODE_Q = 0, MODE_K = 1, MODE_V = 2, MODE_OUT = 3 };

template <int MODE>
__global__ __launch_bounds__(512, 2) void gemm_bt(const u16* __restrict__ A, const u16* __restrict__ Bt,
                                                  const float* __restrict__ bias,
                                                  void* __restrict__ Cout) {
  constexpr int K = 1024, NT = K / 32;
  __shared__ u16 lds[5 * 12288];  // 5 bufs x (A 256x32 = 8192 u16 | B 128x32 = 4096 u16)

  // bijective XCD swizzle (256 blocks, 8 XCDs)
  const int wg = (blockIdx.x & 7) * 32 + (blockIdx.x >> 3);
  const int tm = wg >> 3, tn = wg & 7;
  const int row0 = tm << 8, col0 = tn << 7;

  const int t_ = threadIdx.x, w = t_ >> 6, l = t_ & 63;
  const int wm = w >> 1, wn = w & 1;
  const int fr = l & 15, fo = (l >> 4) << 3;                // frag row / k-elem offset
  const int srow = l >> 2;                                  // staging row-in-16
  const int scol = ((l & 3) ^ ((l >> 3) & 3)) << 3;         // staging col elems (pre-swizzled)

  f32x4 acc[4][4] = {};

  auto stage = [&](int tile) {
    const int kt = tile << 5;
    u16* buf = &lds[(tile % 5) * 12288];
#pragma unroll
    for (int R = 0; R < 2; ++R)
      __builtin_amdgcn_global_load_lds(
          GLBP(A + (size_t)(row0 + R * 128 + w * 16 + srow) * K + kt + scol),
          LDSP(buf + R * 4096 + w * 512), 16, 0, 0);
    __builtin_amdgcn_global_load_lds(
        GLBP(Bt + (size_t)(col0 + w * 16 + srow) * K + kt + scol),
        LDSP(buf + 8192 + w * 512), 16, 0, 0);
  };

  stage(0); stage(1); stage(2); stage(3);

#pragma unroll 1
  for (int t = 0; t < NT; ++t) {
    if (t + 4 < NT) {
      stage(t + 4);
      asm volatile("s_waitcnt vmcnt(12)" ::: "memory");
    } else {
      const int rem = NT - 1 - t;
      if (rem == 3)      asm volatile("s_waitcnt vmcnt(9)" ::: "memory");
      else if (rem == 2) asm volatile("s_waitcnt vmcnt(6)" ::: "memory");
      else if (rem == 1) asm volatile("s_waitcnt vmcnt(3)" ::: "memory");
      else               asm volatile("s_waitcnt vmcnt(0)" ::: "memory");
    }
    __builtin_amdgcn_s_barrier();

    const u16* buf = &lds[(t % 5) * 12288];
    bf16x8 af[4], bf[4];
#pragma unroll
    for (int mi = 0; mi < 4; ++mi) {
      const int r = wm * 64 + mi * 16 + fr;
      af[mi] = *(const bf16x8*)((const char*)buf + r * 64 + ((fo * 2) ^ (((r >> 1) & 3) << 4)));
    }
#pragma unroll
    for (int ni = 0; ni < 4; ++ni) {
      const int r = wn * 64 + ni * 16 + fr;
      bf[ni] = *(const bf16x8*)((const char*)(buf + 8192) + r * 64 +
                                ((fo * 2) ^ (((r >> 1) & 3) << 4)));
    }
    __builtin_amdgcn_s_setprio(1);
#pragma unroll
    for (int mi = 0; mi < 4; ++mi)
#pragma unroll
      for (int ni = 0; ni < 4; ++ni)
        acc[mi][ni] = __builtin_amdgcn_mfma_f32_16x16x32_bf16(af[mi], bf[ni], acc[mi][ni], 0, 0, 0);
    __builtin_amdgcn_s_setprio(0);
    __builtin_amdgcn_s_barrier();
    asm volatile("" ::: "memory");
  }

  // epilogue: C/D layout col = lane&15, row = (lane>>4)*4 + i
  const int rgrp = (l >> 4) << 2;
#pragma unroll
  for (int ni = 0; ni < 4; ++ni) {
    const int n = col0 + wn * 64 + ni * 16 + fr;
    const float bv = bias[n];
#pragma unroll
    for (int mi = 0; mi < 4; ++mi) {
      const int mbase = row0 + wm * 64 + mi * 16 + rgrp;
      if (MODE == MODE_OUT) {
        float* O = (float*)Cout;
#pragma unroll
        for (int i = 0; i < 4; ++i) O[(size_t)(mbase + i) * Dc + n] = acc[mi][ni][i] + bv;
      } else if (MODE == MODE_V) {
        // V transposed + f16: Vt[((b*H+h)*DH + dh)*S + s]
        const int b = mbase >> 11, s = mbase & (Sc - 1);
        const int h = n >> 6, dh = n & 63;
        u16* Vt = (u16*)Cout;
        f16x4v pk;
#pragma unroll
        for (int i = 0; i < 4; ++i) pk[i] = (_Float16)(acc[mi][ni][i] + bv);
        *(f16x4v*)&Vt[((size_t)((b * Hc + h) * DHc + dh)) * Sc + s] = pk;
      } else {
        u16* Oh = (u16*)Cout;  // Qh/Kh: [((b*H+h)*S + s)*DH + dh]
#pragma unroll
        for (int i = 0; i < 4; ++i) {
          const int m = mbase + i;
          const int b = m >> 11, s = m & (Sc - 1);
          const int h = n >> 6, dh = n & 63;
          float vv = acc[mi][ni][i] + bv;
          if (MODE == MODE_Q) vv *= 0.125f * 1.44269504089f;  // fold 1/sqrt(DH) * log2(e)
          Oh[((size_t)((b * Hc + h) * Sc + s)) * DHc + dh] = f2bf(vv);
        }
      }
    }
  }
}

// ---------------- Flash attention: swapped-operand, in-register softmax ----------------
__global__ __launch_bounds__(256, 2) void attn2_kernel(const u16* __restrict__ Qh,
                                                       const u16* __restrict__ Kh,
                                                       const u16* __restrict__ Vt,
                                                       u16* __restrict__ ctx) {
  __shared__ u16 smem[8192];  // 16 KB: K[64][64] bf16 | V^T[64][64] f16
  u16* K_lds = smem;
  u16* V_lds = smem + 4096;

  const int wid = (blockIdx.x & 7) * 128 + (blockIdx.x >> 3);  // XCD swizzle (1024%8==0)
  const int qt = wid & 15, bh = wid >> 4;
  const int t = threadIdx.x, w = t >> 6, l = t & 63;
  const int q = l & 31, h = l >> 5;
  const int q0 = qt * 128 + w * 32;

  bf16x8 qf[4];
  {
    const u16* qp = Qh + ((size_t)bh * Sc + q0 + q) * DHc + h * 8;
#pragma unroll
    for (int kk = 0; kk < 4; ++kk) qf[kk] = *(const bf16x8*)(qp + kk * 16);
  }

  f32x16 oacc[2] = {};
  float m_run = -3.0e38f, l_run = 0.f;

  const int lrow = l >> 3, lg = l & 7;

  for (int kt = 0; kt < Sc; kt += 64) {
    __syncthreads();
#pragma unroll
    for (int c = 0; c < 2; ++c) {
      const int rb = w * 16 + c * 8;
      const int row = rb + lrow;
      const int sg = lg ^ (row & 7);  // pre-swizzled source -> swizzled LDS layout
      __builtin_amdgcn_global_load_lds(GLBP(Kh + ((size_t)bh * Sc + kt + row) * DHc + sg * 8),
                                       LDSP(&K_lds[rb * 64]), 16, 0, 0);
      __builtin_amdgcn_global_load_lds(GLBP(Vt + ((size_t)bh * DHc + row) * Sc + kt + sg * 8),
                                       LDSP(&V_lds[rb * 64]), 16, 0, 0);
    }
    __syncthreads();

    // S^T[k][q] = K · Q^T
    f32x16 sacc[2];
#pragma unroll
    for (int kt32 = 0; kt32 < 2; ++kt32) {
      f32x16 s_ = {};
      const int krow = kt32 * 32 + q;
      __builtin_amdgcn_s_setprio(1);
#pragma unroll
      for (int kk = 0; kk < 4; ++kk) {
        bf16x8 kf = *(const bf16x8*)&K_lds[krow * 64 + ((2 * kk + h) ^ (krow & 7)) * 8];
        s_ = __builtin_amdgcn_mfma_f32_32x32x16_bf16(kf, qf[kk], s_, 0, 0, 0);
      }
      __builtin_amdgcn_s_setprio(0);
      sacc[kt32] = s_;
    }

    // online softmax (log2 domain), defer-max (T13, THR=8 log2 units)
    float mx = sacc[0][0];
#pragma unroll
    for (int r = 1; r < 16; ++r) mx = fmaxf(mx, sacc[0][r]);
#pragma unroll
    for (int r = 0; r < 16; ++r) mx = fmaxf(mx, sacc[1][r]);
    mx = fmaxf(mx, __shfl_xor(mx, 32));
    if (__any(mx - m_run > 8.f)) {
      const float mnew = fmaxf(m_run, mx);
      const float corr = __builtin_amdgcn_exp2f(m_run - mnew);
      m_run = mnew;
      l_run *= corr;
#pragma unroll
      for (int dt = 0; dt < 2; ++dt)
#pragma unroll
        for (int r = 0; r < 16; ++r) oacc[dt][r] *= corr;
    }
    float sum = 0.f;
    f16x4v pa[2][4];  // P fragments, k = kt32*32 + kc*8 + 4h + j
#pragma unroll
    for (int kt32 = 0; kt32 < 2; ++kt32)
#pragma unroll
      for (int kc = 0; kc < 4; ++kc)
#pragma unroll
        for (int j = 0; j < 4; ++j) {
          float pv = __builtin_amdgcn_exp2f(sacc[kt32][kc * 4 + j] - m_run);
          sum += pv;
          pa[kt32][kc][j] = (_Float16)pv;
        }
    sum += __shfl_xor(sum, 32);
    l_run += sum;

    // O^T += V^T · P
    __builtin_amdgcn_s_setprio(1);
#pragma unroll
    for (int kt32 = 0; kt32 < 2; ++kt32)
#pragma unroll
      for (int kc = 0; kc < 4; ++kc)
#pragma unroll
        for (int dt = 0; dt < 2; ++dt) {
          const int vrow = dt * 32 + q;
          f16x4v vf = *(const f16x4v*)&V_lds[vrow * 64 + ((kt32 * 4 + kc) ^ (vrow & 7)) * 8 + 4 * h];
          oacc[dt] = __builtin_amdgcn_mfma_f32_32x32x8f16(vf, pa[kt32][kc], oacc[dt], 0, 0, 0);
        }
    __builtin_amdgcn_s_setprio(0);
  }

  // epilogue: normalize, transpose O^T -> O through LDS, coalesced ctx write
  __syncthreads();
  const float inv = 1.f / l_run;
  u16* E = smem + w * 2048;
#pragma unroll
  for (int dt = 0; dt < 2; ++dt)
#pragma unroll
    for (int rg = 0; rg < 4; ++rg) {
      bf16x4 pk;
#pragma unroll
      for (int j = 0; j < 4; ++j) pk[j] = (__bf16)(oacc[dt][rg * 4 + j] * inv);
      const int dh0 = dt * 32 + rg * 8 + 4 * h;
      int byte = q * 128 + dh0 * 2;
      byte ^= (q & 7) << 4;
      *(bf16x4*)((char*)E + byte) = pk;
    }
  __syncthreads();
  const int b = bh >> 4, head = bh & 15;
  const size_t crow = ((size_t)(b * Sc + q0 + q)) * Dc + head * 64 + h * 32;
#pragma unroll
  for (int i = 0; i < 4; ++i) {
    const int g = (4 * h + i) ^ (q & 7);
    uint4 tv = *(const uint4*)((char*)E + q * 128 + g * 16);
    *(uint4*)((u16*)ctx + crow + i * 8) = tv;
  }
}

// ---------------- launcher ----------------
extern "C" void kernel_launch(void* const* d_in, const int* in_sizes, int n_in,
                              void* d_out, int out_size, void* d_ws, size_t ws_size,
                              hipStream_t stream) {
  const float* q  = (const float*)d_in[0];
  const float* k  = (const float*)d_in[1];
  const float* v  = (const float*)d_in[2];
  const float* Wq = (const float*)d_in[3];
  const float* bq = (const float*)d_in[4];
  const float* Wk = (const float*)d_in[5];
  const float* bk = (const float*)d_in[6];
  const float* Wv = (const float*)d_in[7];
  const float* bv = (const float*)d_in[8];
  const float* Wo = (const float*)d_in[9];
  const float* bo = (const float*)d_in[10];
  float* out = (float*)d_out;

  const size_t MK = (size_t)Mrows * Dc;
  const size_t WK = (size_t)Dc * Dc;
  u16* qb  = (u16*)d_ws;
  u16* kb  = qb + MK;
  u16* vb  = kb + MK;
  u16* Wqb = vb + MK;
  u16* Wkb = Wqb + WK;
  u16* Wvb = Wkb + WK;
  u16* Wob = Wvb + WK;
  u16* Qh  = Wob + WK;
  u16* Kh  = Qh + MK;
  u16* VtB = Kh + MK;
  u16* ctx = VtB + MK;

  cvt3_kernel<<<dim3(2048, 3), 256, 0, stream>>>(q, k, v, (ushort4*)qb, (int)(MK / 4));
  cvt4_kernel<<<dim3(512, 4), 256, 0, stream>>>(Wq, Wk, Wv, Wo, (ushort4*)Wqb, (int)(WK / 4));

  gemm_bt<MODE_Q><<<256, 512, 0, stream>>>(qb, Wqb, bq, (void*)Qh);
  gemm_bt<MODE_K><<<256, 512, 0, stream>>>(kb, Wkb, bk, (void*)Kh);
  gemm_bt<MODE_V><<<256, 512, 0, stream>>>(vb, Wvb, bv, (void*)VtB);

  attn2_kernel<<<1024, 256, 0, stream>>>(Qh, Kh, VtB, ctx);

  gemm_bt<MODE_OUT><<<256, 512, 0, stream>>>(ctx, Wob, bo, (void*)out);
}

// Round 5
// 230.819 us; speedup vs baseline: 1.8937x; 1.0102x over previous
//
#include <hip/hip_runtime.h>

typedef __bf16 bf16x8 __attribute__((ext_vector_type(8)));
typedef __bf16 bf16x4 __attribute__((ext_vector_type(4)));
typedef _Float16 f16x4v __attribute__((ext_vector_type(4)));
typedef float f32x4 __attribute__((ext_vector_type(4)));
typedef float f32x16 __attribute__((ext_vector_type(16)));
typedef unsigned short u16;
typedef unsigned int u32;

constexpr int Bc = 4, Sc = 2048, Dc = 1024, Hc = 16, DHc = 64;
constexpr int Mrows = Bc * Sc;  // 8192
constexpr size_t MK = (size_t)Mrows * Dc;
constexpr size_t WK = (size_t)Dc * Dc;

__device__ __forceinline__ u16 f2bf(float f) {
  u32 u = __float_as_uint(f);
  u = (u + 0x7fffu + ((u >> 16) & 1u)) >> 16;  // RTNE
  return (u16)u;
}

#define LDSP(p) ((__attribute__((address_space(3))) void*)(p))
#define GLBP(p) ((const __attribute__((address_space(1))) void*)(p))

// ---------------- fp32 -> bf16 conversion (fused via blockIdx.y) ----------------
__global__ __launch_bounds__(256) void cvt3_kernel(const float* __restrict__ a,
                                                   const float* __restrict__ b,
                                                   const float* __restrict__ c,
                                                   ushort4* __restrict__ out, int n4) {
  const float4* in = (const float4*)(blockIdx.y == 0 ? a : blockIdx.y == 1 ? b : c);
  ushort4* o = out + (size_t)blockIdx.y * n4;
  int stride = gridDim.x * blockDim.x;
  for (int i = blockIdx.x * blockDim.x + threadIdx.x; i < n4; i += stride) {
    float4 v = in[i];
    ushort4 r;
    r.x = f2bf(v.x); r.y = f2bf(v.y); r.z = f2bf(v.z); r.w = f2bf(v.w);
    o[i] = r;
  }
}

__global__ __launch_bounds__(256) void cvt4_kernel(const float* __restrict__ a,
                                                   const float* __restrict__ b,
                                                   const float* __restrict__ c,
                                                   const float* __restrict__ d,
                                                   ushort4* __restrict__ out, int n4) {
  const float4* in = (const float4*)(blockIdx.y == 0 ? a : blockIdx.y == 1 ? b
                                     : blockIdx.y == 2 ? c : d);
  ushort4* o = out + (size_t)blockIdx.y * n4;
  int stride = gridDim.x * blockDim.x;
  for (int i = blockIdx.x * blockDim.x + threadIdx.x; i < n4; i += stride) {
    float4 v = in[i];
    ushort4 r;
    r.x = f2bf(v.x); r.y = f2bf(v.y); r.z = f2bf(v.z); r.w = f2bf(v.w);
    o[i] = r;
  }
}

// ---------------- GEMM v3: 4-phase/K-tile schedule (m201-style) ----------------
// C[m,n] = sum_k A[m,k]*Bt[n,k] + bias[n].  BM=256, BN=128, BK=64, 512 thr
// (8 waves = 4M x 2N, per-wave 64x64 via mfma_32x32x16_bf16).  Ring-3 LDS
// (144 KB), 6 global_load_lds per wave per K-tile spread over phases,
// counted vmcnt(6) once per K-tile, raw s_barrier per phase.
// LDS granule swizzle: 128B rows, 16B granule g stored at g ^ (row&7)
// (pre-swizzled global source, linear LDS dest -> rule 21 satisfied).
// FUSED3: blockIdx.y in {0,1,2} selects {Q,K,V} input/weight/bias/epilogue;
// else single out-proj (fp32 + bo).
template <int FUSED3>
__global__ __launch_bounds__(512, 2) void gemm8(const u16* __restrict__ A0,
                                                const u16* __restrict__ Bt0,
                                                const float* __restrict__ b0,
                                                const float* __restrict__ b1,
                                                const float* __restrict__ b2,
                                                void* __restrict__ out0) {
  constexpr int K = 1024, NT = 16;
  __shared__ u16 lds[3 * 24576];  // 3 x (A 256x64 = 16384 u16 | B 128x64 = 8192 u16)

  const int y = FUSED3 ? (int)blockIdx.y : 3;
  const u16* A = A0 + (FUSED3 ? (size_t)blockIdx.y * MK : 0);
  const u16* Bt = Bt0 + (FUSED3 ? (size_t)blockIdx.y * WK : 0);
  const float* bias = FUSED3 ? (y == 0 ? b0 : y == 1 ? b1 : b2) : b0;

  // bijective XCD swizzle: 256 blocks, 8 XCDs
  const int wg = (blockIdx.x & 7) * 32 + (blockIdx.x >> 3);
  const int tm = wg >> 3, tn = wg & 7;
  const int row0 = tm << 8, col0 = tn << 7;

  const int t_ = threadIdx.x, w = t_ >> 6, l = t_ & 63;
  const int wm = w >> 1, wn = w & 1;
  const int col = l & 31, hh = l >> 5;  // mfma 32x32 lane roles

  f32x16 acc[2][2] = {};

  auto stA = [&](int tile, int i) {
    u16* buf = &lds[(tile % 3) * 24576];
    const int c = (w * 4 + i) * 64 + l;
    const int r = c >> 3, gl = c & 7;
    __builtin_amdgcn_global_load_lds(
        GLBP(A + (size_t)(row0 + r) * K + (tile << 6) + ((gl ^ (r & 7)) << 3)),
        LDSP(buf + (w * 4 + i) * 512), 16, 0, 0);
  };
  auto stB = [&](int tile, int i) {
    u16* buf = &lds[(tile % 3) * 24576] + 16384;
    const int c = (w * 2 + i) * 64 + l;
    const int r = c >> 3, gl = c & 7;
    __builtin_amdgcn_global_load_lds(
        GLBP(Bt + (size_t)(col0 + r) * K + (tile << 6) + ((gl ^ (r & 7)) << 3)),
        LDSP(buf + (w * 2 + i) * 512), 16, 0, 0);
  };

  // prologue: stage tiles 0 and 1; wait oldest 6 (tile 0) -> ready
#pragma unroll
  for (int i = 0; i < 4; ++i) stA(0, i);
#pragma unroll
  for (int i = 0; i < 2; ++i) stB(0, i);
#pragma unroll
  for (int i = 0; i < 4; ++i) stA(1, i);
#pragma unroll
  for (int i = 0; i < 2; ++i) stB(1, i);
  asm volatile("s_waitcnt vmcnt(6)" ::: "memory");
  __builtin_amdgcn_s_barrier();

  const int ar0 = wm * 64 + col, ar1 = ar0 + 32;
  const int br0 = wn * 64 + col, br1 = br0 + 32;

#pragma unroll 1
  for (int t = 0; t < NT; ++t) {
    const u16* abuf = &lds[(t % 3) * 24576];
    const u16* bbuf = abuf + 16384;
#pragma unroll
    for (int ks = 0; ks < 4; ++ks) {
      // phase ks: ds_read 4 frags + issue stage loads, barrier, MFMA cluster, barrier
      bf16x8 a0 = *(const bf16x8*)&abuf[ar0 * 64 + ((((ks << 1) + hh) ^ (ar0 & 7)) << 3)];
      bf16x8 a1 = *(const bf16x8*)&abuf[ar1 * 64 + ((((ks << 1) + hh) ^ (ar1 & 7)) << 3)];
      bf16x8 bq0 = *(const bf16x8*)&bbuf[br0 * 64 + ((((ks << 1) + hh) ^ (br0 & 7)) << 3)];
      bf16x8 bq1 = *(const bf16x8*)&bbuf[br1 * 64 + ((((ks << 1) + hh) ^ (br1 & 7)) << 3)];
      if (t + 2 < NT) {
        if (ks == 0) { stA(t + 2, 0); stA(t + 2, 1); }
        else if (ks == 1) { stA(t + 2, 2); stA(t + 2, 3); }
        else if (ks == 2) { stB(t + 2, 0); stB(t + 2, 1); }
      }
      __builtin_amdgcn_sched_barrier(0);
      __builtin_amdgcn_s_barrier();
      __builtin_amdgcn_sched_barrier(0);
      __builtin_amdgcn_s_setprio(1);
      acc[0][0] = __builtin_amdgcn_mfma_f32_32x32x16_bf16(a0, bq0, acc[0][0], 0, 0, 0);
      acc[0][1] = __builtin_amdgcn_mfma_f32_32x32x16_bf16(a0, bq1, acc[0][1], 0, 0, 0);
      acc[1][0] = __builtin_amdgcn_mfma_f32_32x32x16_bf16(a1, bq0, acc[1][0], 0, 0, 0);
      acc[1][1] = __builtin_amdgcn_mfma_f32_32x32x16_bf16(a1, bq1, acc[1][1], 0, 0, 0);
      __builtin_amdgcn_s_setprio(0);
      __builtin_amdgcn_sched_barrier(0);
      if (ks == 3) {
        if (t + 2 < NT)      asm volatile("s_waitcnt vmcnt(6)" ::: "memory");
        else if (t + 1 < NT) asm volatile("s_waitcnt vmcnt(0)" ::: "memory");
      }
      __builtin_amdgcn_s_barrier();
    }
  }

  // epilogue: C/D 32x32 layout: col = lane&31, row = (r&3) + 8*(r>>2) + 4*(lane>>5)
#pragma unroll
  for (int mi = 0; mi < 2; ++mi)
#pragma unroll
    for (int ni = 0; ni < 2; ++ni) {
      const int n = col0 + wn * 64 + ni * 32 + col;
      const float bv = bias[n];
      const int mbase = row0 + wm * 64 + mi * 32 + 4 * hh;
      if (y == 3) {  // out-proj: fp32
        float* O = (float*)out0;
#pragma unroll
        for (int r = 0; r < 16; ++r) {
          const int m = mbase + (r & 3) + 8 * (r >> 2);
          O[(size_t)m * Dc + n] = acc[mi][ni][r] + bv;
        }
      } else if (y == 2) {  // V: transposed + f16, Vt[((b*H+h)*DH+dh)*S + s]
        u16* Vt = (u16*)out0 + 2 * MK;
        const int h = n >> 6, dh = n & 63;
#pragma unroll
        for (int qg = 0; qg < 4; ++qg) {
          const int s0 = mbase + 8 * qg;
          const int b = s0 >> 11, s = s0 & (Sc - 1);
          f16x4v pk;
#pragma unroll
          for (int r4 = 0; r4 < 4; ++r4) pk[r4] = (_Float16)(acc[mi][ni][qg * 4 + r4] + bv);
          *(f16x4v*)&Vt[((size_t)((b * Hc + h) * DHc + dh)) * Sc + s] = pk;
        }
      } else {  // Q or K: head-split bf16, Q scaled by 1/8 * log2(e)
        u16* Oh = (u16*)out0 + (size_t)y * MK;
        const float scl = (y == 0) ? 0.125f * 1.44269504089f : 1.f;
        const int h = n >> 6, dh = n & 63;
#pragma unroll
        for (int r = 0; r < 16; ++r) {
          const int m = mbase + (r & 3) + 8 * (r >> 2);
          const int b = m >> 11, s = m & (Sc - 1);
          Oh[((size_t)((b * Hc + h) * Sc + s)) * DHc + dh] = f2bf((acc[mi][ni][r] + bv) * scl);
        }
      }
    }
}

// ---------------- Flash attention: swapped-operand, in-register softmax ----------------
__global__ __launch_bounds__(256, 2) void attn2_kernel(const u16* __restrict__ Qh,
                                                       const u16* __restrict__ Kh,
                                                       const u16* __restrict__ Vt,
                                                       u16* __restrict__ ctx) {
  __shared__ u16 smem[8192];  // 16 KB: K[64][64] bf16 | V^T[64][64] f16
  u16* K_lds = smem;
  u16* V_lds = smem + 4096;

  const int wid = (blockIdx.x & 7) * 128 + (blockIdx.x >> 3);  // XCD swizzle (1024%8==0)
  const int qt = wid & 15, bh = wid >> 4;
  const int t = threadIdx.x, w = t >> 6, l = t & 63;
  const int q = l & 31, h = l >> 5;
  const int q0 = qt * 128 + w * 32;

  bf16x8 qf[4];
  {
    const u16* qp = Qh + ((size_t)bh * Sc + q0 + q) * DHc + h * 8;
#pragma unroll
    for (int kk = 0; kk < 4; ++kk) qf[kk] = *(const bf16x8*)(qp + kk * 16);
  }

  f32x16 oacc[2] = {};
  float m_run = -3.0e38f, l_run = 0.f;

  const int lrow = l >> 3, lg = l & 7;

  for (int kt = 0; kt < Sc; kt += 64) {
    __syncthreads();
#pragma unroll
    for (int c = 0; c < 2; ++c) {
      const int rb = w * 16 + c * 8;
      const int row = rb + lrow;
      const int sg = lg ^ (row & 7);  // pre-swizzled source -> swizzled LDS layout
      __builtin_amdgcn_global_load_lds(GLBP(Kh + ((size_t)bh * Sc + kt + row) * DHc + sg * 8),
                                       LDSP(&K_lds[rb * 64]), 16, 0, 0);
      __builtin_amdgcn_global_load_lds(GLBP(Vt + ((size_t)bh * DHc + row) * Sc + kt + sg * 8),
                                       LDSP(&V_lds[rb * 64]), 16, 0, 0);
    }
    __syncthreads();

    // S^T[k][q] = K · Q^T
    f32x16 sacc[2];
#pragma unroll
    for (int kt32 = 0; kt32 < 2; ++kt32) {
      f32x16 s_ = {};
      const int krow = kt32 * 32 + q;
      __builtin_amdgcn_s_setprio(1);
#pragma unroll
      for (int kk = 0; kk < 4; ++kk) {
        bf16x8 kf = *(const bf16x8*)&K_lds[krow * 64 + ((2 * kk + h) ^ (krow & 7)) * 8];
        s_ = __builtin_amdgcn_mfma_f32_32x32x16_bf16(kf, qf[kk], s_, 0, 0, 0);
      }
      __builtin_amdgcn_s_setprio(0);
      sacc[kt32] = s_;
    }

    // online softmax (log2 domain), defer-max (THR=8), max3-shaped reduction
    float mx;
    {
      float t0 = fmaxf(fmaxf(sacc[0][0], sacc[0][1]), sacc[0][2]);
      float t1 = fmaxf(fmaxf(sacc[0][3], sacc[0][4]), sacc[0][5]);
      float t2 = fmaxf(fmaxf(sacc[0][6], sacc[0][7]), sacc[0][8]);
      float t3 = fmaxf(fmaxf(sacc[0][9], sacc[0][10]), sacc[0][11]);
      float t4 = fmaxf(fmaxf(sacc[0][12], sacc[0][13]), sacc[0][14]);
      float t5 = fmaxf(fmaxf(sacc[0][15], sacc[1][0]), sacc[1][1]);
      float t6 = fmaxf(fmaxf(sacc[1][2], sacc[1][3]), sacc[1][4]);
      float t7 = fmaxf(fmaxf(sacc[1][5], sacc[1][6]), sacc[1][7]);
      float t8 = fmaxf(fmaxf(sacc[1][8], sacc[1][9]), sacc[1][10]);
      float t9 = fmaxf(fmaxf(sacc[1][11], sacc[1][12]), sacc[1][13]);
      float ta = fmaxf(sacc[1][14], sacc[1][15]);
      float u0 = fmaxf(fmaxf(t0, t1), t2);
      float u1 = fmaxf(fmaxf(t3, t4), t5);
      float u2 = fmaxf(fmaxf(t6, t7), t8);
      float u3 = fmaxf(t9, ta);
      mx = fmaxf(fmaxf(u0, u1), fmaxf(u2, u3));
    }
    mx = fmaxf(mx, __shfl_xor(mx, 32));
    if (__any(mx - m_run > 8.f)) {
      const float mnew = fmaxf(m_run, mx);
      const float corr = __builtin_amdgcn_exp2f(m_run - mnew);
      m_run = mnew;
      l_run *= corr;
#pragma unroll
      for (int dt = 0; dt < 2; ++dt)
#pragma unroll
        for (int r = 0; r < 16; ++r) oacc[dt][r] *= corr;
    }
    float sum = 0.f;
    f16x4v pa[2][4];  // P fragments, k = kt32*32 + kc*8 + 4h + j
#pragma unroll
    for (int kt32 = 0; kt32 < 2; ++kt32)
#pragma unroll
      for (int kc = 0; kc < 4; ++kc) {
        float p0 = __builtin_amdgcn_exp2f(sacc[kt32][kc * 4 + 0] - m_run);
        float p1 = __builtin_amdgcn_exp2f(sacc[kt32][kc * 4 + 1] - m_run);
        float p2 = __builtin_amdgcn_exp2f(sacc[kt32][kc * 4 + 2] - m_run);
        float p3 = __builtin_amdgcn_exp2f(sacc[kt32][kc * 4 + 3] - m_run);
        sum += (p0 + p1) + (p2 + p3);
        auto lo = __builtin_amdgcn_cvt_pkrtz(p0, p1);  // __fp16x2
        auto hi = __builtin_amdgcn_cvt_pkrtz(p2, p3);
        f16x4v pk;
        pk[0] = (_Float16)lo[0]; pk[1] = (_Float16)lo[1];
        pk[2] = (_Float16)hi[0]; pk[3] = (_Float16)hi[1];
        pa[kt32][kc] = pk;
      }
    sum += __shfl_xor(sum, 32);
    l_run += sum;

    // O^T += V^T · P
    __builtin_amdgcn_s_setprio(1);
#pragma unroll
    for (int kt32 = 0; kt32 < 2; ++kt32)
#pragma unroll
      for (int kc = 0; kc < 4; ++kc)
#pragma unroll
        for (int dt = 0; dt < 2; ++dt) {
          const int vrow = dt * 32 + q;
          f16x4v vf = *(const f16x4v*)&V_lds[vrow * 64 + ((kt32 * 4 + kc) ^ (vrow & 7)) * 8 + 4 * h];
          oacc[dt] = __builtin_amdgcn_mfma_f32_32x32x8f16(vf, pa[kt32][kc], oacc[dt], 0, 0, 0);
        }
    __builtin_amdgcn_s_setprio(0);
  }

  // epilogue: normalize, transpose O^T -> O through LDS, coalesced ctx write
  __syncthreads();
  const float inv = 1.f / l_run;
  u16* E = smem + w * 2048;
#pragma unroll
  for (int dt = 0; dt < 2; ++dt)
#pragma unroll
    for (int rg = 0; rg < 4; ++rg) {
      bf16x4 pk;
#pragma unroll
      for (int j = 0; j < 4; ++j) pk[j] = (__bf16)(oacc[dt][rg * 4 + j] * inv);
      const int dh0 = dt * 32 + rg * 8 + 4 * h;
      int byte = q * 128 + dh0 * 2;
      byte ^= (q & 7) << 4;
      *(bf16x4*)((char*)E + byte) = pk;
    }
  __syncthreads();
  const int b = bh >> 4, head = bh & 15;
  const size_t crow = ((size_t)(b * Sc + q0 + q)) * Dc + head * 64 + h * 32;
#pragma unroll
  for (int i = 0; i < 4; ++i) {
    const int g = (4 * h + i) ^ (q & 7);
    uint4 tv = *(const uint4*)((char*)E + q * 128 + g * 16);
    *(uint4*)((u16*)ctx + crow + i * 8) = tv;
  }
}

// ---------------- launcher ----------------
extern "C" void kernel_launch(void* const* d_in, const int* in_sizes, int n_in,
                              void* d_out, int out_size, void* d_ws, size_t ws_size,
                              hipStream_t stream) {
  const float* q  = (const float*)d_in[0];
  const float* k  = (const float*)d_in[1];
  const float* v  = (const float*)d_in[2];
  const float* Wq = (const float*)d_in[3];
  const float* bq = (const float*)d_in[4];
  const float* Wk = (const float*)d_in[5];
  const float* bk = (const float*)d_in[6];
  const float* Wv = (const float*)d_in[7];
  const float* bv = (const float*)d_in[8];
  const float* Wo = (const float*)d_in[9];
  const float* bo = (const float*)d_in[10];
  float* out = (float*)d_out;

  u16* qb  = (u16*)d_ws;          // qb,kb,vb contiguous (3*MK)
  u16* Wqb = qb + 3 * MK;         // Wq,Wk,Wv,Wo contiguous (4*WK)
  u16* Qh  = Wqb + 4 * WK;        // Qh,Kh,Vt contiguous (3*MK)
  u16* Kh  = Qh + MK;
  u16* VtB = Kh + MK;
  u16* ctx = VtB + MK;

  cvt3_kernel<<<dim3(2048, 3), 256, 0, stream>>>(q, k, v, (ushort4*)qb, (int)(MK / 4));
  cvt4_kernel<<<dim3(512, 4), 256, 0, stream>>>(Wq, Wk, Wv, Wo, (ushort4*)Wqb, (int)(WK / 4));

  gemm8<1><<<dim3(256, 3), 512, 0, stream>>>(qb, Wqb, bq, bk, bv, (void*)Qh);

  attn2_kernel<<<1024, 256, 0, stream>>>(Qh, Kh, VtB, ctx);

  gemm8<0><<<dim3(256, 1), 512, 0, stream>>>(ctx, Wqb + 3 * WK, bo, bo, bo, (void*)out);
}